// Round 9
// baseline (870.076 us; speedup 1.0000x reference)
//
#include <hip/hip_runtime.h>
#include <math.h>

#define F_   257
#define N_   1000
#define C_   6
#define S_   2
#define K_   4
#define T_   5
#define DLY  6          /* N_TAPS + N_DELAY */
#define EPSF 1e-3f
#define MODEL_EPSF 1e-5f
#define PB_EPSD 1e-6
#define NTHR 512

__device__ __forceinline__ float2 cmul(float2 a, float2 b){
  return make_float2(a.x*b.x - a.y*b.y, a.x*b.y + a.y*b.x);
}
__device__ __forceinline__ float2 cadd(float2 a, float2 b){ return make_float2(a.x+b.x, a.y+b.y); }
__device__ __forceinline__ float2 csub(float2 a, float2 b){ return make_float2(a.x-b.x, a.y-b.y); }

struct dc { double x, y; };
__device__ __forceinline__ dc dmul(dc a, dc b){ return dc{a.x*b.x - a.y*b.y, a.x*b.y + a.y*b.x}; }
__device__ __forceinline__ dc dadd(dc a, dc b){ return dc{a.x+b.x, a.y+b.y}; }
__device__ __forceinline__ dc dsub(dc a, dc b){ return dc{a.x-b.x, a.y-b.y}; }
__device__ __forceinline__ dc ddiv(dc a, dc b){
  double d = b.x*b.x + b.y*b.y;
  return dc{(a.x*b.x + a.y*b.y)/d, (a.y*b.x - a.x*b.y)/d};
}
__device__ __forceinline__ dc d_of(float2 a){ return dc{(double)a.x, (double)a.y}; }

__device__ __forceinline__ float wred(float v){
  #pragma unroll
  for (int off = 32; off; off >>= 1) v += __shfl_xor(v, off);
  return v;
}

// ---------------------------------------------------------------------------
// weights precompute: den[b][s][n] += sum_f |src|^2, gsum[b][s] += total
// ---------------------------------------------------------------------------
__global__ __launch_bounds__(128) void k_weights_x(const float* __restrict__ Xre,
    const float* __restrict__ Xim, float* __restrict__ deng, float* __restrict__ gsumg)
{
  __shared__ float redw[2];
  int blk = blockIdx.x;
  int fc = blk & 15; int ch = (blk >> 4) & 7; int s = (blk >> 7) & 1; int b = blk >> 8;
  int tid = threadIdx.x;
  int n = ch*125 + tid;
  int f0 = fc*17, f1 = (f0 + 17 < F_) ? f0 + 17 : F_;
  float acc = 0.f;
  if (tid < 125){
    for (int f = f0; f < f1; ++f){
      size_t gi = ((size_t)(b*C_+s)*F_ + f)*N_ + n;
      float xr = Xre[gi], xi = Xim[gi];
      acc += xr*xr + xi*xi;
    }
    atomicAdd(&deng[(b*S_+s)*N_ + n], acc);
  }
  float r = (tid < 125) ? acc : 0.f;
  #pragma unroll
  for (int off = 32; off; off >>= 1) r += __shfl_xor(r, off);
  if ((tid & 63) == 0) redw[tid >> 6] = r;
  __syncthreads();
  if (tid == 0) atomicAdd(&gsumg[b*S_+s], redw[0] + redw[1]);
}

__global__ __launch_bounds__(128) void k_weights_y(const float2* __restrict__ Yg,
    float* __restrict__ deng, float* __restrict__ gsumg)
{
  __shared__ float redw[2];
  int blk = blockIdx.x;
  int fc = blk & 15; int ch = (blk >> 4) & 7; int s = (blk >> 7) & 1; int b = blk >> 8;
  int tid = threadIdx.x;
  int n = ch*125 + tid;
  int f0 = fc*17, f1 = (f0 + 17 < F_) ? f0 + 17 : F_;
  float acc = 0.f;
  if (tid < 125){
    for (int f = f0; f < f1; ++f){
      float2 y = Yg[(((size_t)(b*F_+f))*S_ + s)*N_ + n];
      acc += y.x*y.x + y.y*y.y;
    }
    atomicAdd(&deng[(b*S_+s)*N_ + n], acc);
  }
  float r = (tid < 125) ? acc : 0.f;
  #pragma unroll
  for (int off = 32; off; off >>= 1) r += __shfl_xor(r, off);
  if ((tid & 63) == 0) redw[tid >> 6] = r;
  __syncthreads();
  if (tid == 0) atomicAdd(&gsumg[b*S_+s], redw[0] + redw[1]);
}

// ---------------------------------------------------------------------------
// background update; cx/cb pre-offset pointers (LDS or global)
// ---------------------------------------------------------------------------
__device__ __forceinline__ void bg_update(int tid, const float2* Wl,
    const float2* Hl, float2* Al, float2* Jl,
    const float2* cx, const float2* cb)
{
  if (tid < S_*C_){
    int s = tid / C_, j = tid - s*C_;
    float2 a = make_float2(0.f, 0.f);
    #pragma unroll
    for (int i = 0; i < C_; ++i) a = cadd(a, cmul(Wl[s*C_+i], cx[i*C_+j]));
    #pragma unroll
    for (int i = 0; i < C_; ++i)
      #pragma unroll
      for (int t = 0; t < T_; ++t)
        a = cadd(a, cmul(Hl[(s*C_+i)*T_+t], cb[(i*T_+t)*C_+j]));
    Al[s*C_+j] = a;
  }
  __syncthreads();
  if (tid == 0){
    dc M00 = d_of(Al[0]),  M01 = d_of(Al[1]);
    dc M10 = d_of(Al[C_]), M11 = d_of(Al[C_+1]);
    dc det = dsub(dmul(M00, M11), dmul(M01, M10));
    #pragma unroll
    for (int k = 0; k < K_; ++k){
      dc r0 = d_of(Al[2+k]), r1 = d_of(Al[C_+2+k]);
      dc x0 = ddiv(dsub(dmul(M11, r0), dmul(M01, r1)), det);
      dc x1 = ddiv(dsub(dmul(M00, r1), dmul(M10, r0)), det);
      Jl[k*S_+0] = make_float2((float)x0.x, (float)(-x0.y));
      Jl[k*S_+1] = make_float2((float)x1.x, (float)(-x1.y));
    }
  }
  __syncthreads();
}

__device__ __forceinline__ float2 rdc2(const float* c, int i){
  return make_float2(c[i], c[i+1]);
}

// Z chain: c0 = A/D (v=k*6+s*3+{Ar,Ai,D}), c1 = G (v=q*4+s*2+{re,im})
// G pairs: q0..5 = (0,1),(0,2),(0,3),(1,2),(1,3),(2,3)
__device__ __forceinline__ void chainZf(int s, const float* c0, const float* c1, float2* vz)
{
  float2 a0=rdc2(c0,0*6+s*3), a1=rdc2(c0,1*6+s*3), a2=rdc2(c0,2*6+s*3), a3=rdc2(c0,3*6+s*3);
  float D0=c0[0*6+s*3+2], D1=c0[1*6+s*3+2], D2=c0[2*6+s*3+2], D3=c0[3*6+s*3+2];
  float d;
  d = fmaxf(D0, EPSF); vz[0] = make_float2(a0.x/d, a0.y/d);
  a1 = csub(a1, cmul(vz[0], rdc2(c1, 0*4+s*2)));
  a2 = csub(a2, cmul(vz[0], rdc2(c1, 1*4+s*2)));
  a3 = csub(a3, cmul(vz[0], rdc2(c1, 2*4+s*2)));
  d = fmaxf(D1, EPSF); vz[1] = make_float2(a1.x/d, a1.y/d);
  a2 = csub(a2, cmul(vz[1], rdc2(c1, 3*4+s*2)));
  a3 = csub(a3, cmul(vz[1], rdc2(c1, 4*4+s*2)));
  d = fmaxf(D2, EPSF); vz[2] = make_float2(a2.x/d, a2.y/d);
  a3 = csub(a3, cmul(vz[2], rdc2(c1, 5*4+s*2)));
  d = fmaxf(D3, EPSF); vz[3] = make_float2(a3.x/d, a3.y/d);
}

// tap chain: c0 = A/D (v=t*6+s*3+{Ar,Ai,D}), c1 = G (v=q*4+s*2+{re,im})
// G pairs: q0..9 = (0,1),(0,2),(0,3),(0,4),(1,2),(1,3),(1,4),(2,3),(2,4),(3,4)
__device__ __forceinline__ void chainTf(int s, const float* c0, const float* c1, float2* vt)
{
  float2 a0=rdc2(c0,0*6+s*3), a1=rdc2(c0,1*6+s*3), a2=rdc2(c0,2*6+s*3);
  float2 a3=rdc2(c0,3*6+s*3), a4=rdc2(c0,4*6+s*3);
  float D0=c0[0*6+s*3+2], D1=c0[1*6+s*3+2], D2=c0[2*6+s*3+2];
  float D3=c0[3*6+s*3+2], D4=c0[4*6+s*3+2];
  float d;
  d = fmaxf(D0, EPSF); vt[0] = make_float2(a0.x/d, a0.y/d);
  a1 = csub(a1, cmul(vt[0], rdc2(c1, 0*4+s*2)));
  a2 = csub(a2, cmul(vt[0], rdc2(c1, 1*4+s*2)));
  a3 = csub(a3, cmul(vt[0], rdc2(c1, 2*4+s*2)));
  a4 = csub(a4, cmul(vt[0], rdc2(c1, 3*4+s*2)));
  d = fmaxf(D1, EPSF); vt[1] = make_float2(a1.x/d, a1.y/d);
  a2 = csub(a2, cmul(vt[1], rdc2(c1, 4*4+s*2)));
  a3 = csub(a3, cmul(vt[1], rdc2(c1, 5*4+s*2)));
  a4 = csub(a4, cmul(vt[1], rdc2(c1, 6*4+s*2)));
  d = fmaxf(D2, EPSF); vt[2] = make_float2(a2.x/d, a2.y/d);
  a3 = csub(a3, cmul(vt[2], rdc2(c1, 7*4+s*2)));
  a4 = csub(a4, cmul(vt[2], rdc2(c1, 8*4+s*2)));
  d = fmaxf(D3, EPSF); vt[3] = make_float2(a3.x/d, a3.y/d);
  a4 = csub(a4, cmul(vt[3], rdc2(c1, 9*4+s*2)));
  d = fmaxf(D4, EPSF); vt[4] = make_float2(a4.x/d, a4.y/d);
}

// ---------------------------------------------------------------------------
// source ISS round, register Y/w, all-wave reduction.
// ---------------------------------------------------------------------------
template<int SRC>
__device__ __forceinline__ void src_round_reg(int tid, int lane, int wid,
    float (*part)[73], float (*comb)[40], float2* Wl, float2* Hl,
    float2& yA0, float2& yA1, float2& yB0, float2& yB1,
    float wA0, float wA1, float wB0, float wB1)
{
  float2 sA = (SRC==0) ? yA0 : yA1;
  float2 sB = (SRC==0) ? yB0 : yB1;
  float m  = sA.x*sA.x + sA.y*sA.y;
  float mb = sB.x*sB.x + sB.y*sB.y;
  float r0 = wA0*(yA0.x*sA.x + yA0.y*sA.y) + wB0*(yB0.x*sB.x + yB0.y*sB.y);
  float r1 = wA0*(yA0.y*sA.x - yA0.x*sA.y) + wB0*(yB0.y*sB.x - yB0.x*sB.y);
  float r2 = wA0*m + wB0*mb;
  float r3 = wA1*(yA1.x*sA.x + yA1.y*sA.y) + wB1*(yB1.x*sB.x + yB1.y*sB.y);
  float r4 = wA1*(yA1.y*sA.x - yA1.x*sA.y) + wB1*(yB1.y*sB.x - yB1.x*sB.y);
  float r5 = wA1*m + wB1*mb;
  r0 = wred(r0); r1 = wred(r1); r2 = wred(r2);
  r3 = wred(r3); r4 = wred(r4); r5 = wred(r5);
  if (lane == 0){
    part[wid][0]=r0; part[wid][1]=r1; part[wid][2]=r2;
    part[wid][3]=r3; part[wid][4]=r4; part[wid][5]=r5;
  }
  __syncthreads();
  if (tid < 6){
    float s = 0.f;
    #pragma unroll
    for (int w = 0; w < 8; ++w) s += part[w][tid];
    comb[0][tid] = s;
  }
  __syncthreads();
  const float inv = 1.f/(float)N_;
  float t0=comb[0][0]*inv, t1=comb[0][1]*inv, t2=comb[0][2]*inv;
  float t3=comb[0][3]*inv, t4=comb[0][4]*inv, t5=comb[0][5]*inv;
  float d0 = fmaxf(t2, EPSF), d1 = fmaxf(t5, EPSF);
  float2 v0 = make_float2(t0/d0, t1/d0);
  float2 v1 = make_float2(t3/d1, t4/d1);
  if (SRC == 0) v0 = make_float2(1.f - 1.f/sqrtf(d0), 0.f);
  else          v1 = make_float2(1.f - 1.f/sqrtf(d1), 0.f);
  yA0 = csub(yA0, cmul(v0, sA));
  yA1 = csub(yA1, cmul(v1, sA));
  yB0 = csub(yB0, cmul(v0, sB));
  yB1 = csub(yB1, cmul(v1, sB));
  if (tid < C_){
    float2 ws = Wl[SRC*C_+tid];
    Wl[tid]    = csub(Wl[tid],    cmul(v0, ws));
    Wl[C_+tid] = csub(Wl[C_+tid], cmul(v1, ws));
  } else if (tid >= 64 && tid < 64 + C_*T_){
    int i = tid - 64;
    float2 hs = Hl[SRC*C_*T_+i];
    Hl[i]       = csub(Hl[i],       cmul(v0, hs));
    Hl[C_*T_+i] = csub(Hl[C_*T_+i], cmul(v1, hs));
  }
}

// ---------------------------------------------------------------------------
// KM: one full _one_iter for one (b,f); register Y/w/X, all-wave phases.
// ---------------------------------------------------------------------------
template<bool FIRST, bool FINAL>
__global__ __launch_bounds__(512, 4) void k_main(const float* __restrict__ Xre,
    const float* __restrict__ Xim, float2* __restrict__ Yg, float2* __restrict__ Wg,
    float2* __restrict__ Hg, float2* __restrict__ Cxxg,
    float2* __restrict__ Cbxg, const float* __restrict__ deng,
    const float* __restrict__ gsumg, float2* __restrict__ out2)
{
  __shared__ float2 Xl[C_*N_];
  __shared__ float2 Wl[S_*C_];
  __shared__ float2 Hl[S_*C_*T_];
  __shared__ float2 Jl[K_*S_];
  __shared__ float2 Al[S_*C_];
  __shared__ float2 Cxl[C_*C_];
  __shared__ float2 Cbl[C_*T_*C_];
  __shared__ float  part[8][73];
  __shared__ float  comb[2][40];

  int p = blockIdx.x; int b = p / F_; int f = p - b*F_;
  int tid = threadIdx.x;
  int lane = tid & 63, wid = tid >> 6;
  const int nA = tid;
  const int nB = tid + NTHR;
  const bool hasB = (nB < N_);
  const int nBs = hasB ? nB : 0;

  for (int i = tid; i < C_*N_; i += NTHR){
    int c = i / N_, n = i - c*N_;
    size_t gi = ((size_t)(b*C_+c)*F_ + f)*N_ + n;
    Xl[i] = make_float2(Xre[gi], Xim[gi]);
  }

  float gv0 = fmaxf(gsumg[b*S_+0] * (1.f/((float)F_*(float)N_)), EPSF);
  float gv1 = fmaxf(gsumg[b*S_+1] * (1.f/((float)F_*(float)N_)), EPSF);
  float ig0 = 1.f / fmaxf(sqrtf(gv0), EPSF);
  float ig1 = 1.f / fmaxf(sqrtf(gv1), EPSF);

  if (FIRST){
    if (tid < S_*C_){
      int s = tid / C_, c = tid - s*C_;
      Wl[tid] = make_float2((s==c) ? (s ? ig1 : ig0) : 0.f, 0.f);
    }
    if (tid < S_*C_*T_) Hl[tid] = make_float2(0.f, 0.f);
  } else {
    if (tid < S_*C_){
      float ig = (tid / C_) ? ig1 : ig0;
      float2 w = Wg[(size_t)p*S_*C_ + tid];
      Wl[tid] = make_float2(w.x*ig, w.y*ig);
    }
    if (tid < S_*C_*T_){
      float ig = (tid / (C_*T_)) ? ig1 : ig0;
      float2 h = Hg[(size_t)p*S_*C_*T_ + tid];
      Hl[tid] = make_float2(h.x*ig, h.y*ig);
    }
  }
  __syncthreads();   // Xl, Wl, Hl ready

  // ---- covariances (FIRST): 6 phases, one source-channel d each ----
  if (FIRST){
    const float inv_n = 1.0f / (float)N_;
    for (int d = 0; d < C_; ++d){
      float2 lgA[6], lgB[6];
      #pragma unroll
      for (int q = 0; q < 6; ++q){
        const int lag = (q < 5) ? (DLY - q) : 0;
        lgA[q] = (nA >= lag) ? Xl[d*N_ + nA - lag] : make_float2(0.f,0.f);
        lgB[q] = hasB ? Xl[d*N_ + nBs - lag] : make_float2(0.f,0.f);
      }
      float acc[72];
      #pragma unroll
      for (int v = 0; v < 72; ++v) acc[v] = 0.f;
      #pragma unroll
      for (int c2 = 0; c2 < 6; ++c2){
        float2 bA = Xl[c2*N_ + nA];
        float2 bB = hasB ? Xl[c2*N_ + nBs] : make_float2(0.f,0.f);
        #pragma unroll
        for (int q = 0; q < 6; ++q){
          acc[c2*12 + q*2]     += lgA[q].x*bA.x + lgA[q].y*bA.y
                                + lgB[q].x*bB.x + lgB[q].y*bB.y;
          acc[c2*12 + q*2 + 1] += lgA[q].y*bA.x - lgA[q].x*bA.y
                                + lgB[q].y*bB.x - lgB[q].x*bB.y;
        }
      }
      #pragma unroll
      for (int v = 0; v < 72; ++v){
        float r = wred(acc[v]);
        if (lane == 0) part[wid][v] = r;
      }
      __syncthreads();
      if (tid < 72){
        float s = 0.f;
        #pragma unroll
        for (int w = 0; w < 8; ++w) s += part[w][tid];
        s *= inv_n;
        int c2 = tid / 12, r = tid - c2*12, q = r >> 1, im = r & 1;
        if (q == 5){
          ((float*)Cxl)[(d*C_+c2)*2 + im] = s;
          ((float*)(Cxxg + (size_t)p*(C_*C_)))[(d*C_+c2)*2 + im] = s;
        } else {
          int idx = (d*T_ + q)*C_ + c2;
          ((float*)Cbl)[idx*2 + im] = s;
          ((float*)(Cbxg + (size_t)p*(C_*T_*C_)))[idx*2 + im] = s;
        }
      }
      __syncthreads();
    }
  }

  // ---- register state ----
  float2 xA[6], xB[6];
  #pragma unroll
  for (int c = 0; c < 6; ++c){
    xA[c] = Xl[c*N_ + nA];
    xB[c] = hasB ? Xl[c*N_ + nBs] : make_float2(0.f,0.f);
  }
  float wA0 = gv0 / fmaxf(2.f*sqrtf(deng[(b*S_+0)*N_+nA]), MODEL_EPSF);
  float wA1 = gv1 / fmaxf(2.f*sqrtf(deng[(b*S_+1)*N_+nA]), MODEL_EPSF);
  float wB0 = 0.f, wB1 = 0.f;
  if (hasB){
    wB0 = gv0 / fmaxf(2.f*sqrtf(deng[(b*S_+0)*N_+nB]), MODEL_EPSF);
    wB1 = gv1 / fmaxf(2.f*sqrtf(deng[(b*S_+1)*N_+nB]), MODEL_EPSF);
  }
  float2 yA0, yA1, yB0 = make_float2(0.f,0.f), yB1 = make_float2(0.f,0.f);
  if (FIRST){
    yA0 = make_float2(xA[0].x*ig0, xA[0].y*ig0);
    yA1 = make_float2(xA[1].x*ig1, xA[1].y*ig1);
    if (hasB){
      yB0 = make_float2(xB[0].x*ig0, xB[0].y*ig0);
      yB1 = make_float2(xB[1].x*ig1, xB[1].y*ig1);
    }
  } else {
    float2 t0 = Yg[((size_t)p*S_+0)*N_+nA];
    float2 t1 = Yg[((size_t)p*S_+1)*N_+nA];
    yA0 = make_float2(t0.x*ig0, t0.y*ig0);
    yA1 = make_float2(t1.x*ig1, t1.y*ig1);
    if (hasB){
      float2 u0 = Yg[((size_t)p*S_+0)*N_+nB];
      float2 u1 = Yg[((size_t)p*S_+1)*N_+nB];
      yB0 = make_float2(u0.x*ig0, u0.y*ig0);
      yB1 = make_float2(u1.x*ig1, u1.y*ig1);
    }
  }

  const float2* cx = FIRST ? (const float2*)Cxl : (const float2*)(Cxxg + (size_t)p*C_*C_);
  const float2* cb = FIRST ? (const float2*)Cbl : (const float2*)(Cbxg + (size_t)p*C_*T_*C_);

  bg_update(tid, Wl, Hl, Al, Jl, cx, cb);

  // ---- source rounds ----
  src_round_reg<0>(tid, lane, wid, part, comb, Wl, Hl, yA0,yA1,yB0,yB1, wA0,wA1,wB0,wB1);
  src_round_reg<1>(tid, lane, wid, part, comb, Wl, Hl, yA0,yA1,yB0,yB1, wA0,wA1,wB0,wB1);

  // ---- Z group ----
  {
    float2 zA[4], zB[4];
    #pragma unroll
    for (int k = 0; k < 4; ++k){
      zA[k] = csub(cadd(cmul(Jl[2*k], xA[0]), cmul(Jl[2*k+1], xA[1])), xA[2+k]);
      zB[k] = csub(cadd(cmul(Jl[2*k], xB[0]), cmul(Jl[2*k+1], xB[1])), xB[2+k]);
    }
    // A+D phase
    {
      float acc[24];
      #pragma unroll
      for (int k = 0; k < 4; ++k){
        float mA = zA[k].x*zA[k].x + zA[k].y*zA[k].y;
        float mB = zB[k].x*zB[k].x + zB[k].y*zB[k].y;
        acc[k*6+0] = wA0*(yA0.x*zA[k].x + yA0.y*zA[k].y) + wB0*(yB0.x*zB[k].x + yB0.y*zB[k].y);
        acc[k*6+1] = wA0*(yA0.y*zA[k].x - yA0.x*zA[k].y) + wB0*(yB0.y*zB[k].x - yB0.x*zB[k].y);
        acc[k*6+2] = wA0*mA + wB0*mB;
        acc[k*6+3] = wA1*(yA1.x*zA[k].x + yA1.y*zA[k].y) + wB1*(yB1.x*zB[k].x + yB1.y*zB[k].y);
        acc[k*6+4] = wA1*(yA1.y*zA[k].x - yA1.x*zA[k].y) + wB1*(yB1.y*zB[k].x - yB1.x*zB[k].y);
        acc[k*6+5] = wA1*mA + wB1*mB;
      }
      #pragma unroll
      for (int v = 0; v < 24; ++v){
        float r = wred(acc[v]);
        if (lane == 0) part[wid][v] = r;
      }
      __syncthreads();
      if (tid < 24){
        float s = 0.f;
        #pragma unroll
        for (int w = 0; w < 8; ++w) s += part[w][tid];
        comb[0][tid] = s;
      }
      __syncthreads();
    }
    // G phase
    {
      float acc[24];
      constexpr int ZA_[6] = {0,0,0,1,1,2};
      constexpr int ZB_[6] = {1,2,3,2,3,3};
      #pragma unroll
      for (int q = 0; q < 6; ++q){
        float2 a1 = zA[ZA_[q]], b1 = zA[ZB_[q]];
        float2 a2 = zB[ZA_[q]], b2 = zB[ZB_[q]];
        float prA = a1.x*b1.x + a1.y*b1.y, piA = a1.y*b1.x - a1.x*b1.y;
        float prB = a2.x*b2.x + a2.y*b2.y, piB = a2.y*b2.x - a2.x*b2.y;
        acc[q*4+0] = wA0*prA + wB0*prB;
        acc[q*4+1] = wA0*piA + wB0*piB;
        acc[q*4+2] = wA1*prA + wB1*prB;
        acc[q*4+3] = wA1*piA + wB1*piB;
      }
      #pragma unroll
      for (int v = 0; v < 24; ++v){
        float r = wred(acc[v]);
        if (lane == 0) part[wid][v] = r;
      }
      __syncthreads();
      if (tid < 24){
        float s = 0.f;
        #pragma unroll
        for (int w = 0; w < 8; ++w) s += part[w][tid];
        comb[1][tid] = s;
      }
      __syncthreads();
    }
    // chain + updates
    {
      float2 vz0[4], vz1[4];
      chainZf(0, comb[0], comb[1], vz0);
      chainZf(1, comb[0], comb[1], vz1);
      #pragma unroll
      for (int k = 0; k < 4; ++k){
        yA0 = csub(yA0, cmul(vz0[k], zA[k]));
        yA1 = csub(yA1, cmul(vz1[k], zA[k]));
        yB0 = csub(yB0, cmul(vz0[k], zB[k]));
        yB1 = csub(yB1, cmul(vz1[k], zB[k]));
      }
      if (tid == 0){
        float2 a0 = cadd(cadd(cmul(vz0[0],Jl[0]), cmul(vz0[1],Jl[2])),
                         cadd(cmul(vz0[2],Jl[4]), cmul(vz0[3],Jl[6])));
        float2 a1 = cadd(cadd(cmul(vz0[0],Jl[1]), cmul(vz0[1],Jl[3])),
                         cadd(cmul(vz0[2],Jl[5]), cmul(vz0[3],Jl[7])));
        Wl[0] = csub(Wl[0], a0);
        Wl[1] = csub(Wl[1], a1);
        Wl[S_+0] = cadd(Wl[S_+0], vz0[0]);
        Wl[S_+1] = cadd(Wl[S_+1], vz0[1]);
        Wl[S_+2] = cadd(Wl[S_+2], vz0[2]);
        Wl[S_+3] = cadd(Wl[S_+3], vz0[3]);
        float2 b0 = cadd(cadd(cmul(vz1[0],Jl[0]), cmul(vz1[1],Jl[2])),
                         cadd(cmul(vz1[2],Jl[4]), cmul(vz1[3],Jl[6])));
        float2 b1 = cadd(cadd(cmul(vz1[0],Jl[1]), cmul(vz1[1],Jl[3])),
                         cadd(cmul(vz1[2],Jl[5]), cmul(vz1[3],Jl[7])));
        Wl[C_+0] = csub(Wl[C_+0], b0);
        Wl[C_+1] = csub(Wl[C_+1], b1);
        Wl[C_+S_+0] = cadd(Wl[C_+S_+0], vz1[0]);
        Wl[C_+S_+1] = cadd(Wl[C_+S_+1], vz1[1]);
        Wl[C_+S_+2] = cadd(Wl[C_+S_+2], vz1[2]);
        Wl[C_+S_+3] = cadd(Wl[C_+S_+3], vz1[3]);
      }
    }
  }

  // ---- tap groups ----
  for (int c = 0; c < C_; ++c){
    float2 tlA[5], tlB[5];
    #pragma unroll
    for (int t = 0; t < 5; ++t){
      const int lag = DLY - t;
      tlA[t] = (nA >= lag) ? Xl[c*N_ + nA - lag] : make_float2(0.f,0.f);
      tlB[t] = hasB ? Xl[c*N_ + nBs - lag] : make_float2(0.f,0.f);
    }
    // A+D phase
    {
      float acc[30];
      #pragma unroll
      for (int t = 0; t < 5; ++t){
        float mA = tlA[t].x*tlA[t].x + tlA[t].y*tlA[t].y;
        float mB = tlB[t].x*tlB[t].x + tlB[t].y*tlB[t].y;
        acc[t*6+0] = wA0*(yA0.x*tlA[t].x + yA0.y*tlA[t].y) + wB0*(yB0.x*tlB[t].x + yB0.y*tlB[t].y);
        acc[t*6+1] = wA0*(yA0.y*tlA[t].x - yA0.x*tlA[t].y) + wB0*(yB0.y*tlB[t].x - yB0.x*tlB[t].y);
        acc[t*6+2] = wA0*mA + wB0*mB;
        acc[t*6+3] = wA1*(yA1.x*tlA[t].x + yA1.y*tlA[t].y) + wB1*(yB1.x*tlB[t].x + yB1.y*tlB[t].y);
        acc[t*6+4] = wA1*(yA1.y*tlA[t].x - yA1.x*tlA[t].y) + wB1*(yB1.y*tlB[t].x - yB1.x*tlB[t].y);
        acc[t*6+5] = wA1*mA + wB1*mB;
      }
      #pragma unroll
      for (int v = 0; v < 30; ++v){
        float r = wred(acc[v]);
        if (lane == 0) part[wid][v] = r;
      }
      __syncthreads();
      if (tid < 30){
        float s = 0.f;
        #pragma unroll
        for (int w = 0; w < 8; ++w) s += part[w][tid];
        comb[0][tid] = s;
      }
      __syncthreads();
    }
    // G phase
    {
      float acc[40];
      constexpr int TA_[10] = {0,0,0,0,1,1,1,2,2,3};
      constexpr int TB_[10] = {1,2,3,4,2,3,4,3,4,4};
      #pragma unroll
      for (int q = 0; q < 10; ++q){
        float2 a1 = tlA[TA_[q]], b1 = tlA[TB_[q]];
        float2 a2 = tlB[TA_[q]], b2 = tlB[TB_[q]];
        float prA = a1.x*b1.x + a1.y*b1.y, piA = a1.y*b1.x - a1.x*b1.y;
        float prB = a2.x*b2.x + a2.y*b2.y, piB = a2.y*b2.x - a2.x*b2.y;
        acc[q*4+0] = wA0*prA + wB0*prB;
        acc[q*4+1] = wA0*piA + wB0*piB;
        acc[q*4+2] = wA1*prA + wB1*prB;
        acc[q*4+3] = wA1*piA + wB1*piB;
      }
      #pragma unroll
      for (int v = 0; v < 40; ++v){
        float r = wred(acc[v]);
        if (lane == 0) part[wid][v] = r;
      }
      __syncthreads();
      if (tid < 40){
        float s = 0.f;
        #pragma unroll
        for (int w = 0; w < 8; ++w) s += part[w][tid];
        comb[1][tid] = s;
      }
      __syncthreads();
    }
    // chain + updates
    {
      float2 vt0[5], vt1[5];
      chainTf(0, comb[0], comb[1], vt0);
      chainTf(1, comb[0], comb[1], vt1);
      #pragma unroll
      for (int t = 0; t < 5; ++t){
        yA0 = csub(yA0, cmul(vt0[t], tlA[t]));
        yA1 = csub(yA1, cmul(vt1[t], tlA[t]));
        yB0 = csub(yB0, cmul(vt0[t], tlB[t]));
        yB1 = csub(yB1, cmul(vt1[t], tlB[t]));
      }
      if (tid == 0){
        #pragma unroll
        for (int t = 0; t < 5; ++t){
          Hl[(0*C_+c)*T_+t] = cadd(Hl[(0*C_+c)*T_+t], vt0[t]);
          Hl[(1*C_+c)*T_+t] = cadd(Hl[(1*C_+c)*T_+t], vt1[t]);
        }
      }
    }
  }
  __syncthreads();   // Wl/Hl updates visible

  if (!FINAL){
    Yg[((size_t)p*S_+0)*N_+nA] = yA0;
    Yg[((size_t)p*S_+1)*N_+nA] = yA1;
    if (hasB){
      Yg[((size_t)p*S_+0)*N_+nB] = yB0;
      Yg[((size_t)p*S_+1)*N_+nB] = yB1;
    }
    if (tid < S_*C_)    Wg[(size_t)p*S_*C_ + tid]    = Wl[tid];
    if (tid < S_*C_*T_) Hg[(size_t)p*S_*C_*T_ + tid] = Hl[tid];
  } else {
    bg_update(tid, Wl, Hl, Al, Jl, cx, cb);   // final J

    float2 oA0 = make_float2(0.f,0.f), oA1 = oA0, oB0 = oA0, oB1 = oA0;
    #pragma unroll
    for (int d = 0; d < C_; ++d){
      float2 x = Xl[d*N_+nA];
      oA0 = cadd(oA0, cmul(Wl[d],    x));
      oA1 = cadd(oA1, cmul(Wl[C_+d], x));
    }
    #pragma unroll
    for (int t = 0; t < T_; ++t){
      int m = nA - (DLY - t);
      if (m >= 0){
        #pragma unroll
        for (int d = 0; d < C_; ++d){
          float2 x = Xl[d*N_+m];
          oA0 = csub(oA0, cmul(Hl[d*T_+t],      x));
          oA1 = csub(oA1, cmul(Hl[(C_+d)*T_+t], x));
        }
      }
    }
    if (hasB){
      #pragma unroll
      for (int d = 0; d < C_; ++d){
        float2 x = Xl[d*N_+nB];
        oB0 = cadd(oB0, cmul(Wl[d],    x));
        oB1 = cadd(oB1, cmul(Wl[C_+d], x));
      }
      #pragma unroll
      for (int t = 0; t < T_; ++t){
        int m = nB - (DLY - t);
        #pragma unroll
        for (int d = 0; d < C_; ++d){
          float2 x = Xl[d*N_+m];
          oB0 = csub(oB0, cmul(Hl[d*T_+t],      x));
          oB1 = csub(oB1, cmul(Hl[(C_+d)*T_+t], x));
        }
      }
    }

    if (tid == 0){
      dc Bm[2][2];
      #pragma unroll
      for (int s2 = 0; s2 < S_; ++s2)
        #pragma unroll
        for (int k = 0; k < S_; ++k){
          dc acc = d_of(Wl[s2*C_+k]);
          #pragma unroll
          for (int cc = 0; cc < K_; ++cc)
            acc = dadd(acc, dmul(d_of(Wl[s2*C_+S_+cc]), d_of(Jl[cc*S_+k])));
          Bm[s2][k] = acc;
        }
      dc G00 = dc{Bm[0][0].x + PB_EPSD, Bm[0][0].y};
      dc G01 = Bm[1][0];
      dc G10 = Bm[0][1];
      dc G11 = dc{Bm[1][1].x + PB_EPSD, Bm[1][1].y};
      dc det = dsub(dmul(G00, G11), dmul(G01, G10));
      dc a0 = ddiv(G11, det);
      dc a1 = ddiv(dc{-G10.x, -G10.y}, det);
      Al[0] = make_float2((float)a0.x, (float)a0.y);
      Al[1] = make_float2((float)a1.x, (float)a1.y);
    }
    __syncthreads();
    float2 s0 = Al[0], s1 = Al[1];
    out2[((size_t)(b*S_+0)*F_ + f)*N_ + nA] = cmul(oA0, s0);
    out2[((size_t)(b*S_+1)*F_ + f)*N_ + nA] = cmul(oA1, s1);
    if (hasB){
      out2[((size_t)(b*S_+0)*F_ + f)*N_ + nB] = cmul(oB0, s0);
      out2[((size_t)(b*S_+1)*F_ + f)*N_ + nB] = cmul(oB1, s1);
    }
  }
}

// ---------------------------------------------------------------------------
extern "C" void kernel_launch(void* const* d_in, const int* in_sizes, int n_in,
                              void* d_out, int out_size, void* d_ws, size_t ws_size,
                              hipStream_t stream)
{
  const float* Xre = (const float*)d_in[0];
  const float* Xim = (const float*)d_in[1];
  int B = in_sizes[0] / (C_*F_*N_);
  int P = B*F_;

  float2* Yg    = (float2*)d_ws;
  float2* Wg    = Yg    + (size_t)P*S_*N_;
  float2* Hg    = Wg    + (size_t)P*S_*C_;
  float2* Cxxg  = Hg    + (size_t)P*S_*C_*T_;
  float2* Cbxg  = Cxxg  + (size_t)P*C_*C_;
  float*  deng0 = (float*)(Cbxg + (size_t)P*C_*T_*C_);
  float*  deng1 = deng0 + (size_t)B*S_*N_;
  float*  gsum0 = deng1 + (size_t)B*S_*N_;
  float*  gsum1 = gsum0 + (size_t)B*S_;
  float2* out2  = (float2*)d_out;

  size_t zeroBytes = (2*(size_t)B*S_*N_ + 2*(size_t)B*S_) * sizeof(float);
  int WG = B*S_*8*16;

  hipMemsetAsync(deng0, 0, zeroBytes, stream);
  // iteration 0 (covariances computed inside k_main<FIRST>)
  k_weights_x<<<WG, 128, 0, stream>>>(Xre, Xim, deng0, gsum0);
  k_main<true,false><<<P, 512, 0, stream>>>(Xre, Xim, Yg, Wg, Hg, Cxxg, Cbxg,
                                            deng0, gsum0, nullptr);
  // iteration 1 + finalization
  k_weights_y<<<WG, 128, 0, stream>>>(Yg, deng1, gsum1);
  k_main<false,true><<<P, 512, 0, stream>>>(Xre, Xim, Yg, Wg, Hg, Cxxg, Cbxg,
                                            deng1, gsum1, out2);
}